// Round 13
// baseline (366.004 us; speedup 1.0000x reference)
//
#include <hip/hip_runtime.h>

// GCN forward, reassociated + bf16 tables + MFMA GEMMs + binned ELL build
// + XCD-feature-sliced SpMMs (v4: 8-slot pipelined gather loop):
//   y1s = bf16(x @ W1)            (MFMA, fused with binA; sliced [8][NP][16])
//   h2s = relu(A @ y1s + b1)      (sliced SpMM: slice->XCD via blockIdx&7)
//   y2s = bf16(h2 @ W2)           (MFMA, sliced [4][NP][16])
//   out = A @ y2s + b2            (sliced SpMM, 4 slices, float4 out)
// R21: v3 fixed ELL bytes (FETCH 163->64MB) but time barely moved (86.7->
// 79.4): latency-exposure bound (VALUBusy 48%, HBM 14%) — serial chain
// ELL-load -> 4 gathers -> FMA exposes ~1 L2 round-trip per 4 slots. v4:
// 2-stage software pipeline (prefetch next 8-slot pair while FMA-ing
// current; 8 gathers issued back-to-back) + NT on streaming ELL reads so
// they stop evicting the L2-resident slice.

typedef __attribute__((ext_vector_type(8))) short short8;
typedef __attribute__((ext_vector_type(4))) float floatx4;
typedef __attribute__((ext_vector_type(2))) float floatx2;
typedef __attribute__((ext_vector_type(4))) unsigned int uintx4;
typedef __attribute__((ext_vector_type(2))) unsigned int uintx2;

#define ELLS 64    // ELL stride (slots/row)
#define RW   256   // rows per binB bucket (LDS tile 64 KB)
#define CH   4096  // edges per binA chunk
#define EPT  16    // edges per thread in binA (4096/256)
#define MAXB 400   // static LDS bound for bucket count (N=100K -> 391)

static __device__ __forceinline__ unsigned short f2bf(float f) {
    unsigned int u = __builtin_bit_cast(unsigned int, f);
    u += 0x7fffu + ((u >> 16) & 1u);        // round-to-nearest-even
    return (unsigned short)(u >> 16);
}
static __device__ __forceinline__ float bflo(unsigned int u) {
    return __builtin_bit_cast(float, u << 16);
}
static __device__ __forceinline__ float bfhi(unsigned int u) {
    return __builtin_bit_cast(float, u & 0xffff0000u);
}
// packed ELL slot: low 17 bits = col, high 15 bits = val*32767
static __device__ __forceinline__ float slotval(unsigned int s) {
    return (float)(s >> 17) * (1.0f / 32767.0f);
}

// ---------------------------------------------------------------------------
// Prep: W1[128,128] -> W1t[128][128] bf16; W2[128,64] -> W2t[64][128] bf16
// ---------------------------------------------------------------------------
__global__ __launch_bounds__(256) void prep_kernel(
    const float* __restrict__ W1, const float* __restrict__ W2,
    unsigned short* __restrict__ W1t, unsigned short* __restrict__ W2t)
{
    int idx = blockIdx.x * 256 + threadIdx.x;
    if (idx < 128 * 128) {
        int n = idx >> 7, k = idx & 127;
        W1t[idx] = f2bf(W1[(size_t)k * 128 + n]);
    }
    if (idx < 64 * 128) {
        int n = idx >> 7, k = idx & 127;
        W2t[idx] = f2bf(W2[(size_t)k * 64 + n]);
    }
}

// ---------------------------------------------------------------------------
// gemm1: Y_s[slice][row][16] = bf16(x[row] @ W1[:,slice*16+..]).
// Verified gfx950 layouts: A/B frag [lane&15][quad*8+j]; C/D col=lane&15,
// row=quad*4+reg. x read exactly once -> NT. nt == slice.
// ---------------------------------------------------------------------------
static __device__ __forceinline__ void gemm1_body(
    const float* __restrict__ A, const unsigned short* __restrict__ Wt,
    unsigned short* __restrict__ Ys, int NP, int N, int bid)
{
    const int lane = threadIdx.x & 63;
    const int wave = threadIdx.x >> 6;
    const int quad = lane >> 4;
    const int l16  = lane & 15;
    const int row0 = bid * 64 + wave * 16;
    int arow = row0 + l16;
    if (arow > N - 1) arow = N - 1;      // clamp: stores guarded below

    short8 af[4];
    const float* ap = A + (size_t)arow * 128 + quad * 8;
    #pragma unroll
    for (int kt = 0; kt < 4; ++kt) {
        const floatx4* p = (const floatx4*)(ap + kt * 32);
        floatx4 lo = __builtin_nontemporal_load(p);
        floatx4 hi = __builtin_nontemporal_load(p + 1);
        short8 t;
        t[0] = (short)f2bf(lo[0]); t[1] = (short)f2bf(lo[1]);
        t[2] = (short)f2bf(lo[2]); t[3] = (short)f2bf(lo[3]);
        t[4] = (short)f2bf(hi[0]); t[5] = (short)f2bf(hi[1]);
        t[6] = (short)f2bf(hi[2]); t[7] = (short)f2bf(hi[3]);
        af[kt] = t;
    }

    floatx4 acc[8];
    #pragma unroll
    for (int nt = 0; nt < 8; ++nt) acc[nt] = (floatx4){0.f, 0.f, 0.f, 0.f};

    #pragma unroll
    for (int nt = 0; nt < 8; ++nt) {
        const unsigned short* wp = Wt + (size_t)(nt * 16 + l16) * 128 + quad * 8;
        #pragma unroll
        for (int kt = 0; kt < 4; ++kt) {
            short8 bfr = *(const short8*)(wp + kt * 32);
            acc[nt] = __builtin_amdgcn_mfma_f32_16x16x32_bf16(
                af[kt], bfr, acc[nt], 0, 0, 0);
        }
    }

    #pragma unroll
    for (int nt = 0; nt < 8; ++nt) {
        #pragma unroll
        for (int r = 0; r < 4; ++r) {
            int row = row0 + quad * 4 + r;
            if (row < N)
                Ys[(size_t)nt * NP * 16 + (size_t)row * 16 + l16] =
                    f2bf(acc[nt][r]);
        }
    }
}

// ---------------------------------------------------------------------------
// Fused dispatch: blocks [0,NC): binA (histogram/compact/coalesced slab
// flush); blocks [NC,..): gemm1. slab entry: .x = col|(row_in_bucket<<17),
// .y = fp32 val bits.
// ---------------------------------------------------------------------------
__global__ __launch_bounds__(256) void binA_gemm1_fused(
    const int* __restrict__ erow, const int* __restrict__ ecol,
    const float* __restrict__ eval,
    uint2* __restrict__ slab, unsigned int* __restrict__ offsT,
    int E, int NC, int NB,
    const float* __restrict__ x, const unsigned short* __restrict__ W1t,
    unsigned short* __restrict__ y1s, int NP, int N)
{
    __shared__ unsigned int hist[MAXB + 1];
    __shared__ uint2 compact[CH];

    if ((int)blockIdx.x < NC) {
        const int t     = threadIdx.x;
        const int chunk = blockIdx.x;

        for (int i = t; i <= NB; i += 256) hist[i] = 0;
        __syncthreads();

        int base = chunk * CH + t * EPT;
        unsigned int w0[EPT];   // col | (row_in_bucket << 17)
        unsigned int vb[EPT];   // fp32 val bits
        int bk[EPT], rk[EPT];

        if (base + EPT <= E) {
            #pragma unroll
            for (int q = 0; q < 4; ++q) {
                int4   r4 = *(const int4*)(erow + base + q * 4);
                int4   c4 = *(const int4*)(ecol + base + q * 4);
                float4 v4 = *(const float4*)(eval + base + q * 4);
                int rr[4]   = {r4.x, r4.y, r4.z, r4.w};
                int cc[4]   = {c4.x, c4.y, c4.z, c4.w};
                float vv[4] = {v4.x, v4.y, v4.z, v4.w};
                #pragma unroll
                for (int j = 0; j < 4; ++j) {
                    int i = q * 4 + j;
                    bk[i] = rr[j] >> 8;
                    w0[i] = (unsigned int)cc[j]
                          | (((unsigned int)rr[j] & (RW - 1)) << 17);
                    vb[i] = __builtin_bit_cast(unsigned int, vv[j]);
                }
            }
        } else {
            #pragma unroll
            for (int j = 0; j < EPT; ++j) {
                int e = base + j;
                if (e < E) {
                    int r = erow[e];
                    bk[j] = r >> 8;
                    w0[j] = (unsigned int)ecol[e]
                          | (((unsigned int)r & (RW - 1)) << 17);
                    vb[j] = __builtin_bit_cast(unsigned int, eval[e]);
                } else {
                    bk[j] = NB;  // sentinel bucket, skipped by binB
                    w0[j] = 0u; vb[j] = 0u;
                }
            }
        }

        #pragma unroll
        for (int j = 0; j < EPT; ++j)
            rk[j] = (int)atomicAdd(&hist[bk[j]], 1u);
        __syncthreads();

        if (t == 0) {            // exclusive prefix over NB+1 buckets
            unsigned int run = 0;
            for (int i = 0; i <= NB; ++i) {
                unsigned int c = hist[i];
                hist[i] = run;
                run += c;
            }
        }
        __syncthreads();

        #pragma unroll
        for (int j = 0; j < EPT; ++j) {
            unsigned int pos = hist[bk[j]] + (unsigned int)rk[j];
            uint2 e; e.x = w0[j]; e.y = vb[j];
            compact[pos] = e;
        }
        __syncthreads();

        uint2* sp = slab + (size_t)chunk * CH;
        #pragma unroll
        for (int s = 0; s < EPT; ++s)
            sp[s * 256 + t] = compact[s * 256 + t];
        unsigned int* op = offsT + (size_t)chunk * (NB + 1);
        for (int i = t; i <= NB; i += 256) op[i] = hist[i];
    } else {
        gemm1_body(x, W1t, y1s, NP, N, blockIdx.x - NC);
    }
}

// ---------------------------------------------------------------------------
// binB: block b builds the ELL tile for rows [b*RW,(b+1)*RW) in LDS from the
// slab's per-chunk segments, then flushes SLOT-MAJOR:
//   dst per bucket: [grp 16][s4 16][r 16] x uint4  (grp = row group of 16)
// LDS store uses a 4-slot rotation swizzle (blk = (p/4 + rin) & 15) so the
// flush read is conflict-light; flush writes are dst-contiguous.
// Also emits deg[row] and dmax[group] (max deg over the group's 16 rows).
// ---------------------------------------------------------------------------
__global__ __launch_bounds__(256) void binB(
    const uint2* __restrict__ slab, const unsigned int* __restrict__ offsT,
    unsigned int* __restrict__ ell, int* __restrict__ deg,
    int* __restrict__ dmax, int NC, int NB, int N)
{
    __shared__ unsigned int ell_lds[RW * ELLS];   // 64 KB
    __shared__ unsigned int cur[RW];

    const int t = threadIdx.x;
    const int b = blockIdx.x;

    for (int i = t; i < RW; i += 256) cur[i] = 0;
    __syncthreads();

    const int grp = t >> 5;     // 8 chunk-groups of 32 lanes
    const int sl  = t & 31;
    for (int cbase = 0; cbase < NC; cbase += 8) {
        int c = cbase + grp;
        if (c < NC) {
            const unsigned int* op = offsT + (size_t)c * (NB + 1) + b;
            unsigned int off = op[0];
            unsigned int end = op[1];
            const uint2* sp = slab + (size_t)c * CH;
            for (unsigned int i = off + (unsigned)sl; i < end; i += 32) {
                uint2 e = sp[i];
                unsigned int rin = e.x >> 17;
                unsigned int col = e.x & 0x1FFFFu;
                float v = __builtin_bit_cast(float, e.y);
                unsigned int q = (unsigned int)(int)(v * 32767.f + 0.5f);
                unsigned int p = atomicAdd(&cur[rin], 1u);
                if (p < ELLS) {
                    unsigned int blk = ((p >> 2) + rin) & 15u;  // swizzle
                    ell_lds[rin * ELLS + blk * 4 + (p & 3)] = col | (q << 17);
                }
            }
        }
    }
    __syncthreads();

    // slot-major flush: du = s*256 + s4*16 + r (uint4), dst-contiguous in t
    uint4* dst = (uint4*)(ell + (size_t)b * RW * ELLS);
    const int s4 = t >> 4;
    const int r  = t & 15;
    #pragma unroll
    for (int s = 0; s < 16; ++s) {
        unsigned int sblk = (unsigned)((s4 + r) & 15);
        uint4 q = *(const uint4*)(ell_lds + ((s * 16 + r) * ELLS + sblk * 4));
        dst[s * 256 + s4 * 16 + r] = q;
    }

    int row = b * RW + t;
    if (row < N) deg[row] = min((int)cur[t], ELLS);
    if (t < 16) {
        int m = 0;
        #pragma unroll
        for (int i = 0; i < 16; ++i)
            m = max(m, (int)cur[t * 16 + i]);
        dmax[b * 16 + t] = min(m, ELLS);
    }
}

// ---------------------------------------------------------------------------
// spmm1_sliced v4: h2s[slice][row][16] = relu(A @ y1s[slice] + b1[slice]).
// grid = rtiles(64 rows)*8, slice = blockIdx&7 -> XCD affinity.
// Wave = 16-row group; lane = r(4b) x fl(2b). 2-stage pipeline: slot-block
// pair (8 slots) prefetched one iteration ahead (NT: streaming, keep the
// 3.2MB slice L2-resident); 8 independent uint2 gathers issued back-to-back.
// ---------------------------------------------------------------------------
__global__ __launch_bounds__(256) void spmm1_sliced(
    const int* __restrict__ deg, const int* __restrict__ dmax,
    const unsigned int* __restrict__ ell,
    const unsigned short* __restrict__ y1s, const float* __restrict__ b1,
    unsigned short* __restrict__ h2s, int NP, int N)
{
    const int slice = blockIdx.x & 7;
    const int rblk  = blockIdx.x >> 3;
    const int wave  = threadIdx.x >> 6;
    const int lane  = threadIdx.x & 63;
    const int r     = lane >> 2;          // row within group (0..15)
    const int fl    = lane & 3;           // feat-uint2 pair (0..3)
    const int g     = rblk * 4 + wave;    // 16-row group
    const int row   = g * 16 + r;

    int d   = (row < N) ? deg[row] : 0;
    int nb8 = (dmax[g] + 7) >> 3;         // 8-slot iterations

    const uintx4* eg = (const uintx4*)ell + (size_t)g * 256;
    const unsigned int* xu = (const unsigned int*)y1s + (size_t)slice * NP * 8;

    float a0 = 0.f, a1 = 0.f, a2 = 0.f, a3 = 0.f;

    uintx4 qa = __builtin_nontemporal_load(eg + r);        // slot-block 0
    uintx4 qb = __builtin_nontemporal_load(eg + 16 + r);   // slot-block 1

    for (int i8 = 0; i8 < nb8; ++i8) {
        unsigned int s[8] = {qa[0], qa[1], qa[2], qa[3],
                             qb[0], qb[1], qb[2], qb[3]};
        int pb = 2 * i8 + 2; if (pb > 14) pb = 14;  // clamp; tail predicated
        qa = __builtin_nontemporal_load(eg + pb * 16 + r);
        qb = __builtin_nontemporal_load(eg + (pb + 1) * 16 + r);

        const int base = i8 * 8;
        uint2 u[8];
        #pragma unroll
        for (int j = 0; j < 8; ++j) {
            s[j] = (base + j < d) ? s[j] : 0u;   // pad -> col 0 (hot line)
            u[j] = *((const uint2*)(xu + (s[j] & 0x1FFFFu) * 8) + fl);
        }
        #pragma unroll
        for (int j = 0; j < 8; ++j) {
            float v = slotval(s[j]);
            a0 = fmaf(v, bflo(u[j].x), a0);
            a1 = fmaf(v, bfhi(u[j].x), a1);
            a2 = fmaf(v, bflo(u[j].y), a2);
            a3 = fmaf(v, bfhi(u[j].y), a3);
        }
    }

    if (row < N) {
        float4 b = ((const float4*)b1)[slice * 4 + fl];
        unsigned int p0 = (unsigned int)f2bf(fmaxf(a0 + b.x, 0.f))
                        | ((unsigned int)f2bf(fmaxf(a1 + b.y, 0.f)) << 16);
        unsigned int p1 = (unsigned int)f2bf(fmaxf(a2 + b.z, 0.f))
                        | ((unsigned int)f2bf(fmaxf(a3 + b.w, 0.f)) << 16);
        uintx2 o; o[0] = p0; o[1] = p1;
        __builtin_nontemporal_store(o,
            (uintx2*)((unsigned int*)h2s + (size_t)slice * NP * 8
                      + (size_t)row * 8 + fl * 2));
    }
}

// ---------------------------------------------------------------------------
// gemm2: y2s[nt][row][16] = bf16(h2[row] @ W2[:,nt*16+..]). A-frags read
// from the sliced h2s layout: feat f -> slice f/16, idx f%16.
// ---------------------------------------------------------------------------
__global__ __launch_bounds__(256) void gemm2_kernel(
    const unsigned short* __restrict__ h2s,
    const unsigned short* __restrict__ W2t,
    unsigned short* __restrict__ y2s, int NP, int N)
{
    const int lane = threadIdx.x & 63;
    const int wave = threadIdx.x >> 6;
    const int quad = lane >> 4;
    const int l16  = lane & 15;
    const int row0 = blockIdx.x * 64 + wave * 16;
    int arow = row0 + l16;
    if (arow > N - 1) arow = N - 1;

    short8 af[4];
    #pragma unroll
    for (int kt = 0; kt < 4; ++kt) {
        int slice = kt * 2 + (quad >> 1);
        af[kt] = *(const short8*)(h2s + (size_t)slice * NP * 16
                                  + (size_t)arow * 16 + (quad & 1) * 8);
    }

    floatx4 acc[4];
    #pragma unroll
    for (int nt = 0; nt < 4; ++nt) acc[nt] = (floatx4){0.f, 0.f, 0.f, 0.f};

    #pragma unroll
    for (int nt = 0; nt < 4; ++nt) {
        const unsigned short* wp = W2t + (size_t)(nt * 16 + l16) * 128 + quad * 8;
        #pragma unroll
        for (int kt = 0; kt < 4; ++kt) {
            short8 bfr = *(const short8*)(wp + kt * 32);
            acc[nt] = __builtin_amdgcn_mfma_f32_16x16x32_bf16(
                af[kt], bfr, acc[nt], 0, 0, 0);
        }
    }

    #pragma unroll
    for (int nt = 0; nt < 4; ++nt) {
        #pragma unroll
        for (int r = 0; r < 4; ++r) {
            int row = row0 + quad * 4 + r;
            if (row < N)
                y2s[(size_t)nt * NP * 16 + (size_t)row * 16 + l16] =
                    f2bf(acc[nt][r]);
        }
    }
}

// ---------------------------------------------------------------------------
// spmm2_sliced v4: out[row][slice*16+..] = A @ y2s[slice] + b2[slice].
// 4 slices; same pipelined zero-staging structure; float4 NT output.
// ---------------------------------------------------------------------------
__global__ __launch_bounds__(256) void spmm2_sliced(
    const int* __restrict__ deg, const int* __restrict__ dmax,
    const unsigned int* __restrict__ ell,
    const unsigned short* __restrict__ y2s, const float* __restrict__ b2,
    float* __restrict__ out, int NP, int N)
{
    const int slice = blockIdx.x & 3;
    const int rblk  = blockIdx.x >> 2;
    const int wave  = threadIdx.x >> 6;
    const int lane  = threadIdx.x & 63;
    const int r     = lane >> 2;
    const int fl    = lane & 3;
    const int g     = rblk * 4 + wave;
    const int row   = g * 16 + r;

    int d   = (row < N) ? deg[row] : 0;
    int nb8 = (dmax[g] + 7) >> 3;

    const uintx4* eg = (const uintx4*)ell + (size_t)g * 256;
    const unsigned int* xu = (const unsigned int*)y2s + (size_t)slice * NP * 8;

    float a0 = 0.f, a1 = 0.f, a2 = 0.f, a3 = 0.f;

    uintx4 qa = __builtin_nontemporal_load(eg + r);
    uintx4 qb = __builtin_nontemporal_load(eg + 16 + r);

    for (int i8 = 0; i8 < nb8; ++i8) {
        unsigned int s[8] = {qa[0], qa[1], qa[2], qa[3],
                             qb[0], qb[1], qb[2], qb[3]};
        int pb = 2 * i8 + 2; if (pb > 14) pb = 14;
        qa = __builtin_nontemporal_load(eg + pb * 16 + r);
        qb = __builtin_nontemporal_load(eg + (pb + 1) * 16 + r);

        const int base = i8 * 8;
        uint2 u[8];
        #pragma unroll
        for (int j = 0; j < 8; ++j) {
            s[j] = (base + j < d) ? s[j] : 0u;
            u[j] = *((const uint2*)(xu + (s[j] & 0x1FFFFu) * 8) + fl);
        }
        #pragma unroll
        for (int j = 0; j < 8; ++j) {
            float v = slotval(s[j]);
            a0 = fmaf(v, bflo(u[j].x), a0);
            a1 = fmaf(v, bfhi(u[j].x), a1);
            a2 = fmaf(v, bflo(u[j].y), a2);
            a3 = fmaf(v, bfhi(u[j].y), a3);
        }
    }

    if (row < N) {
        float4 b = ((const float4*)b2)[slice * 4 + fl];
        floatx4 o;
        o[0] = a0 + b.x; o[1] = a1 + b.y; o[2] = a2 + b.z; o[3] = a3 + b.w;
        __builtin_nontemporal_store(
            o, (floatx4*)(out + (size_t)row * 64 + slice * 16 + fl * 4));
    }
}

extern "C" void kernel_launch(void* const* d_in, const int* in_sizes, int n_in,
                              void* d_out, int out_size, void* d_ws, size_t ws_size,
                              hipStream_t stream)
{
    const float* x    = (const float*)d_in[0];
    const int*   erow = (const int*)  d_in[1];
    const int*   ecol = (const int*)  d_in[2];
    const float* eval = (const float*)d_in[3];
    const float* W1   = (const float*)d_in[4];
    const float* b1   = (const float*)d_in[5];
    const float* W2   = (const float*)d_in[6];
    const float* b2   = (const float*)d_in[7];
    float*       out  = (float*)d_out;

    const int N = in_sizes[0] / 128;   // 100000
    const int E = in_sizes[1];         // 1600000
    const int NP = N + 128;            // pad
    const int NB = (N + RW - 1) / RW;  // 391 buckets
    const int NC = (E + CH - 1) / CH;  // 391 chunks

    // Workspace (~91 MB). y2s aliases slab (slab dead after binB; 4KB
    // overflow lands in offsT, also dead after binB).
    unsigned short* y1s = (unsigned short*)d_ws;            // [8][NP][16]
    unsigned short* h2s = y1s + (size_t)NP * 128;           // [8][NP][16]
    unsigned short* W1t = h2s + (size_t)NP * 128;           // [128][128]
    unsigned short* W2t = W1t + 128 * 128;                  // [64][128]
    unsigned int* ell   = (unsigned int*)(W2t + 64 * 128);  // slot-major tiles
    uint2* slab         = (uint2*)(ell + (size_t)NB * RW * ELLS);  // [NC*CH]
    unsigned int* offsT = (unsigned int*)(slab + (size_t)NC * CH); // [NC*(NB+1)]
    int* deg            = (int*)(offsT + (size_t)NC * (NB + 1));   // [N]
    int* dmax           = deg + N;                          // [NB*16]
    unsigned short* y2s = (unsigned short*)slab;            // [4][NP][16] alias

    const int mfma_blocks = (N + 63) / 64;                // 1563
    const int prep_blocks = (128 * 128 + 255) / 256;      // 64
    const int rtiles      = (N + 63) / 64;                // 1563
    const int s1_blocks   = rtiles * 8;                   // 12504
    const int s2_blocks   = rtiles * 4;                   // 6252

    // ---- Prep: cast/transpose weights ----
    prep_kernel<<<prep_blocks, 256, 0, stream>>>(W1, W2, W1t, W2t);

    // ---- binA (chunk binning, coalesced slab) + gemm1 = bf16(x@W1) ----
    binA_gemm1_fused<<<NC + mfma_blocks, 256, 0, stream>>>(
        erow, ecol, eval, slab, offsT, E, NC, NB, x, W1t, y1s, NP, N);

    // ---- binB: bucket -> slot-major ELL tile in LDS -> coalesced flush ----
    binB<<<NB, 256, 0, stream>>>(slab, offsT, ell, deg, dmax, NC, NB, N);

    // ---- Layer-1 SpMM, XCD-sliced v4: h2s = relu(A@y1s + b1) ----
    spmm1_sliced<<<s1_blocks, 256, 0, stream>>>(
        deg, dmax, ell, y1s, b1, h2s, NP, N);

    // ---- gemm2: y2s = bf16(h2 @ W2) ----
    gemm2_kernel<<<mfma_blocks, 256, 0, stream>>>(h2s, W2t, y2s, NP, N);

    // ---- Layer-2 SpMM, XCD-sliced v4: out = A@y2s + b2 ----
    spmm2_sliced<<<s2_blocks, 256, 0, stream>>>(
        deg, dmax, ell, y2s, b2, out, NP, N);
}

// Round 14
// 317.274 us; speedup vs baseline: 1.1536x; 1.1536x over previous
//
#include <hip/hip_runtime.h>

// GCN forward, reassociated + bf16 tables + MFMA GEMMs + binned ELL build
// + XCD-feature-sliced SpMMs (v5: 2-group ILP gather loop):
//   y1s = bf16(x @ W1)            (MFMA, fused with binA; sliced [8][NP][16])
//   h2s = relu(A @ y1s + b1)      (sliced SpMM: slice->XCD via blockIdx&7)
//   y2s = bf16(h2 @ W2)           (MFMA, sliced [4][NP][16])
//   out = A @ y2s + b2            (sliced SpMM, 4 slices, float4 out)
// R22: v4 (NT + manual prefetch) REGRESSED (79.4->106.9: NT raised per-load
// latency; VALUBusy 48->32). Revert to v3 loads. v3's limit = single
// dependency chain per wave (latency-exposure at VALUBusy 48%, HBM 14%).
// v5: each wave owns TWO 16-row groups; per iteration both groups' slot
// blocks are loaded and all 8 gathers issued back-to-back -> two
// independent FMA chains give the scheduler ILP to hide L2 round-trips.

typedef __attribute__((ext_vector_type(8))) short short8;
typedef __attribute__((ext_vector_type(4))) float floatx4;
typedef __attribute__((ext_vector_type(2))) float floatx2;

#define ELLS 64    // ELL stride (slots/row)
#define RW   256   // rows per binB bucket (LDS tile 64 KB)
#define CH   4096  // edges per binA chunk
#define EPT  16    // edges per thread in binA (4096/256)
#define MAXB 400   // static LDS bound for bucket count (N=100K -> 391)

static __device__ __forceinline__ unsigned short f2bf(float f) {
    unsigned int u = __builtin_bit_cast(unsigned int, f);
    u += 0x7fffu + ((u >> 16) & 1u);        // round-to-nearest-even
    return (unsigned short)(u >> 16);
}
static __device__ __forceinline__ float bflo(unsigned int u) {
    return __builtin_bit_cast(float, u << 16);
}
static __device__ __forceinline__ float bfhi(unsigned int u) {
    return __builtin_bit_cast(float, u & 0xffff0000u);
}
// packed ELL slot: low 17 bits = col, high 15 bits = val*32767
static __device__ __forceinline__ float slotval(unsigned int s) {
    return (float)(s >> 17) * (1.0f / 32767.0f);
}

// ---------------------------------------------------------------------------
// Prep: W1[128,128] -> W1t[128][128] bf16; W2[128,64] -> W2t[64][128] bf16
// ---------------------------------------------------------------------------
__global__ __launch_bounds__(256) void prep_kernel(
    const float* __restrict__ W1, const float* __restrict__ W2,
    unsigned short* __restrict__ W1t, unsigned short* __restrict__ W2t)
{
    int idx = blockIdx.x * 256 + threadIdx.x;
    if (idx < 128 * 128) {
        int n = idx >> 7, k = idx & 127;
        W1t[idx] = f2bf(W1[(size_t)k * 128 + n]);
    }
    if (idx < 64 * 128) {
        int n = idx >> 7, k = idx & 127;
        W2t[idx] = f2bf(W2[(size_t)k * 64 + n]);
    }
}

// ---------------------------------------------------------------------------
// gemm1: Y_s[slice][row][16] = bf16(x[row] @ W1[:,slice*16+..]).
// Verified gfx950 layouts: A/B frag [lane&15][quad*8+j]; C/D col=lane&15,
// row=quad*4+reg. x read exactly once -> NT. nt == slice.
// ---------------------------------------------------------------------------
static __device__ __forceinline__ void gemm1_body(
    const float* __restrict__ A, const unsigned short* __restrict__ Wt,
    unsigned short* __restrict__ Ys, int NP, int N, int bid)
{
    const int lane = threadIdx.x & 63;
    const int wave = threadIdx.x >> 6;
    const int quad = lane >> 4;
    const int l16  = lane & 15;
    const int row0 = bid * 64 + wave * 16;
    int arow = row0 + l16;
    if (arow > N - 1) arow = N - 1;      // clamp: stores guarded below

    short8 af[4];
    const float* ap = A + (size_t)arow * 128 + quad * 8;
    #pragma unroll
    for (int kt = 0; kt < 4; ++kt) {
        const floatx4* p = (const floatx4*)(ap + kt * 32);
        floatx4 lo = __builtin_nontemporal_load(p);
        floatx4 hi = __builtin_nontemporal_load(p + 1);
        short8 t;
        t[0] = (short)f2bf(lo[0]); t[1] = (short)f2bf(lo[1]);
        t[2] = (short)f2bf(lo[2]); t[3] = (short)f2bf(lo[3]);
        t[4] = (short)f2bf(hi[0]); t[5] = (short)f2bf(hi[1]);
        t[6] = (short)f2bf(hi[2]); t[7] = (short)f2bf(hi[3]);
        af[kt] = t;
    }

    floatx4 acc[8];
    #pragma unroll
    for (int nt = 0; nt < 8; ++nt) acc[nt] = (floatx4){0.f, 0.f, 0.f, 0.f};

    #pragma unroll
    for (int nt = 0; nt < 8; ++nt) {
        const unsigned short* wp = Wt + (size_t)(nt * 16 + l16) * 128 + quad * 8;
        #pragma unroll
        for (int kt = 0; kt < 4; ++kt) {
            short8 bfr = *(const short8*)(wp + kt * 32);
            acc[nt] = __builtin_amdgcn_mfma_f32_16x16x32_bf16(
                af[kt], bfr, acc[nt], 0, 0, 0);
        }
    }

    #pragma unroll
    for (int nt = 0; nt < 8; ++nt) {
        #pragma unroll
        for (int r = 0; r < 4; ++r) {
            int row = row0 + quad * 4 + r;
            if (row < N)
                Ys[(size_t)nt * NP * 16 + (size_t)row * 16 + l16] =
                    f2bf(acc[nt][r]);
        }
    }
}

// ---------------------------------------------------------------------------
// Fused dispatch: blocks [0,NC): binA (histogram/compact/coalesced slab
// flush); blocks [NC,..): gemm1. slab entry: .x = col|(row_in_bucket<<17),
// .y = fp32 val bits.
// ---------------------------------------------------------------------------
__global__ __launch_bounds__(256) void binA_gemm1_fused(
    const int* __restrict__ erow, const int* __restrict__ ecol,
    const float* __restrict__ eval,
    uint2* __restrict__ slab, unsigned int* __restrict__ offsT,
    int E, int NC, int NB,
    const float* __restrict__ x, const unsigned short* __restrict__ W1t,
    unsigned short* __restrict__ y1s, int NP, int N)
{
    __shared__ unsigned int hist[MAXB + 1];
    __shared__ uint2 compact[CH];

    if ((int)blockIdx.x < NC) {
        const int t     = threadIdx.x;
        const int chunk = blockIdx.x;

        for (int i = t; i <= NB; i += 256) hist[i] = 0;
        __syncthreads();

        int base = chunk * CH + t * EPT;
        unsigned int w0[EPT];   // col | (row_in_bucket << 17)
        unsigned int vb[EPT];   // fp32 val bits
        int bk[EPT], rk[EPT];

        if (base + EPT <= E) {
            #pragma unroll
            for (int q = 0; q < 4; ++q) {
                int4   r4 = *(const int4*)(erow + base + q * 4);
                int4   c4 = *(const int4*)(ecol + base + q * 4);
                float4 v4 = *(const float4*)(eval + base + q * 4);
                int rr[4]   = {r4.x, r4.y, r4.z, r4.w};
                int cc[4]   = {c4.x, c4.y, c4.z, c4.w};
                float vv[4] = {v4.x, v4.y, v4.z, v4.w};
                #pragma unroll
                for (int j = 0; j < 4; ++j) {
                    int i = q * 4 + j;
                    bk[i] = rr[j] >> 8;
                    w0[i] = (unsigned int)cc[j]
                          | (((unsigned int)rr[j] & (RW - 1)) << 17);
                    vb[i] = __builtin_bit_cast(unsigned int, vv[j]);
                }
            }
        } else {
            #pragma unroll
            for (int j = 0; j < EPT; ++j) {
                int e = base + j;
                if (e < E) {
                    int r = erow[e];
                    bk[j] = r >> 8;
                    w0[j] = (unsigned int)ecol[e]
                          | (((unsigned int)r & (RW - 1)) << 17);
                    vb[j] = __builtin_bit_cast(unsigned int, eval[e]);
                } else {
                    bk[j] = NB;  // sentinel bucket, skipped by binB
                    w0[j] = 0u; vb[j] = 0u;
                }
            }
        }

        #pragma unroll
        for (int j = 0; j < EPT; ++j)
            rk[j] = (int)atomicAdd(&hist[bk[j]], 1u);
        __syncthreads();

        if (t == 0) {            // exclusive prefix over NB+1 buckets
            unsigned int run = 0;
            for (int i = 0; i <= NB; ++i) {
                unsigned int c = hist[i];
                hist[i] = run;
                run += c;
            }
        }
        __syncthreads();

        #pragma unroll
        for (int j = 0; j < EPT; ++j) {
            unsigned int pos = hist[bk[j]] + (unsigned int)rk[j];
            uint2 e; e.x = w0[j]; e.y = vb[j];
            compact[pos] = e;
        }
        __syncthreads();

        uint2* sp = slab + (size_t)chunk * CH;
        #pragma unroll
        for (int s = 0; s < EPT; ++s)
            sp[s * 256 + t] = compact[s * 256 + t];
        unsigned int* op = offsT + (size_t)chunk * (NB + 1);
        for (int i = t; i <= NB; i += 256) op[i] = hist[i];
    } else {
        gemm1_body(x, W1t, y1s, NP, N, blockIdx.x - NC);
    }
}

// ---------------------------------------------------------------------------
// binB: block b builds the ELL tile for rows [b*RW,(b+1)*RW) in LDS from the
// slab's per-chunk segments, then flushes SLOT-MAJOR:
//   dst per bucket: [grp 16][s4 16][r 16] x uint4  (grp = row group of 16)
// LDS store uses a 4-slot rotation swizzle (blk = (p/4 + rin) & 15) so the
// flush read is conflict-light; flush writes are dst-contiguous.
// Also emits deg[row] and dmax[group] (max deg over the group's 16 rows).
// ---------------------------------------------------------------------------
__global__ __launch_bounds__(256) void binB(
    const uint2* __restrict__ slab, const unsigned int* __restrict__ offsT,
    unsigned int* __restrict__ ell, int* __restrict__ deg,
    int* __restrict__ dmax, int NC, int NB, int N)
{
    __shared__ unsigned int ell_lds[RW * ELLS];   // 64 KB
    __shared__ unsigned int cur[RW];

    const int t = threadIdx.x;
    const int b = blockIdx.x;

    for (int i = t; i < RW; i += 256) cur[i] = 0;
    __syncthreads();

    const int grp = t >> 5;     // 8 chunk-groups of 32 lanes
    const int sl  = t & 31;
    for (int cbase = 0; cbase < NC; cbase += 8) {
        int c = cbase + grp;
        if (c < NC) {
            const unsigned int* op = offsT + (size_t)c * (NB + 1) + b;
            unsigned int off = op[0];
            unsigned int end = op[1];
            const uint2* sp = slab + (size_t)c * CH;
            for (unsigned int i = off + (unsigned)sl; i < end; i += 32) {
                uint2 e = sp[i];
                unsigned int rin = e.x >> 17;
                unsigned int col = e.x & 0x1FFFFu;
                float v = __builtin_bit_cast(float, e.y);
                unsigned int q = (unsigned int)(int)(v * 32767.f + 0.5f);
                unsigned int p = atomicAdd(&cur[rin], 1u);
                if (p < ELLS) {
                    unsigned int blk = ((p >> 2) + rin) & 15u;  // swizzle
                    ell_lds[rin * ELLS + blk * 4 + (p & 3)] = col | (q << 17);
                }
            }
        }
    }
    __syncthreads();

    // slot-major flush: du = s*256 + s4*16 + r (uint4), dst-contiguous in t
    uint4* dst = (uint4*)(ell + (size_t)b * RW * ELLS);
    const int s4 = t >> 4;
    const int r  = t & 15;
    #pragma unroll
    for (int s = 0; s < 16; ++s) {
        unsigned int sblk = (unsigned)((s4 + r) & 15);
        uint4 q = *(const uint4*)(ell_lds + ((s * 16 + r) * ELLS + sblk * 4));
        dst[s * 256 + s4 * 16 + r] = q;
    }

    int row = b * RW + t;
    if (row < N) deg[row] = min((int)cur[t], ELLS);
    if (t < 16) {
        int m = 0;
        #pragma unroll
        for (int i = 0; i < 16; ++i)
            m = max(m, (int)cur[t * 16 + i]);
        dmax[b * 16 + t] = min(m, ELLS);
    }
}

// ---------------------------------------------------------------------------
// spmm1_sliced v5: h2s[slice][row][16] = relu(A @ y1s[slice] + b1[slice]).
// grid = (NGRP/8)*8 blocks, slice = blockIdx&7 -> XCD affinity.
// Wave owns TWO 16-row groups (gA=blk*8+wave, gB=gA+4); per iteration both
// slot-blocks are loaded (plain loads; L2/L3-served) and all 8 gathers
// issued back-to-back -> two independent FMA chains (ILP latency hiding).
// ---------------------------------------------------------------------------
__global__ __launch_bounds__(256) void spmm1_sliced(
    const int* __restrict__ deg, const int* __restrict__ dmax,
    const unsigned int* __restrict__ ell,
    const unsigned short* __restrict__ y1s, const float* __restrict__ b1,
    unsigned short* __restrict__ h2s, int NP, int N)
{
    const int slice = blockIdx.x & 7;
    const int blk   = blockIdx.x >> 3;
    const int wave  = threadIdx.x >> 6;
    const int lane  = threadIdx.x & 63;
    const int r     = lane >> 2;          // row within group (0..15)
    const int fl    = lane & 3;           // feat-uint2 pair (0..3)
    const int gA    = blk * 8 + wave;
    const int gB    = gA + 4;
    const int rowA  = gA * 16 + r;
    const int rowB  = gB * 16 + r;

    int dA = (rowA < N) ? deg[rowA] : 0;
    int dB = (rowB < N) ? deg[rowB] : 0;
    int nbA = (dmax[gA] + 3) >> 2;
    int nbB = (dmax[gB] + 3) >> 2;
    int nb = max(nbA, nbB);

    const uint4* egA = (const uint4*)ell + (size_t)gA * 256;
    const uint4* egB = (const uint4*)ell + (size_t)gB * 256;
    const unsigned int* xu = (const unsigned int*)y1s + (size_t)slice * NP * 8;

    float a0 = 0.f, a1 = 0.f, a2 = 0.f, a3 = 0.f;
    float c0 = 0.f, c1 = 0.f, c2 = 0.f, c3 = 0.f;

    for (int i4 = 0; i4 < nb; ++i4) {
        uint4 qa = make_uint4(0u, 0u, 0u, 0u);
        uint4 qb = make_uint4(0u, 0u, 0u, 0u);
        if (i4 < nbA) qa = egA[i4 * 16 + r];   // wave-uniform branch
        if (i4 < nbB) qb = egB[i4 * 16 + r];
        unsigned int sa[4] = {qa.x, qa.y, qa.z, qa.w};
        unsigned int sb[4] = {qb.x, qb.y, qb.z, qb.w};
        uint2 ua[4], ub[4];
        #pragma unroll
        for (int j = 0; j < 4; ++j) {
            sa[j] = (i4 * 4 + j < dA) ? sa[j] : 0u;
            ua[j] = *((const uint2*)(xu + (sa[j] & 0x1FFFFu) * 8) + fl);
        }
        #pragma unroll
        for (int j = 0; j < 4; ++j) {
            sb[j] = (i4 * 4 + j < dB) ? sb[j] : 0u;
            ub[j] = *((const uint2*)(xu + (sb[j] & 0x1FFFFu) * 8) + fl);
        }
        #pragma unroll
        for (int j = 0; j < 4; ++j) {
            float v = slotval(sa[j]);
            a0 = fmaf(v, bflo(ua[j].x), a0);
            a1 = fmaf(v, bfhi(ua[j].x), a1);
            a2 = fmaf(v, bflo(ua[j].y), a2);
            a3 = fmaf(v, bfhi(ua[j].y), a3);
        }
        #pragma unroll
        for (int j = 0; j < 4; ++j) {
            float v = slotval(sb[j]);
            c0 = fmaf(v, bflo(ub[j].x), c0);
            c1 = fmaf(v, bfhi(ub[j].x), c1);
            c2 = fmaf(v, bflo(ub[j].y), c2);
            c3 = fmaf(v, bfhi(ub[j].y), c3);
        }
    }

    float4 b = ((const float4*)b1)[slice * 4 + fl];
    if (rowA < N) {
        unsigned int p0 = (unsigned int)f2bf(fmaxf(a0 + b.x, 0.f))
                        | ((unsigned int)f2bf(fmaxf(a1 + b.y, 0.f)) << 16);
        unsigned int p1 = (unsigned int)f2bf(fmaxf(a2 + b.z, 0.f))
                        | ((unsigned int)f2bf(fmaxf(a3 + b.w, 0.f)) << 16);
        uint2 o; o.x = p0; o.y = p1;
        *(uint2*)((unsigned int*)h2s + (size_t)slice * NP * 8
                  + (size_t)rowA * 8 + fl * 2) = o;
    }
    if (rowB < N) {
        unsigned int p0 = (unsigned int)f2bf(fmaxf(c0 + b.x, 0.f))
                        | ((unsigned int)f2bf(fmaxf(c1 + b.y, 0.f)) << 16);
        unsigned int p1 = (unsigned int)f2bf(fmaxf(c2 + b.z, 0.f))
                        | ((unsigned int)f2bf(fmaxf(c3 + b.w, 0.f)) << 16);
        uint2 o; o.x = p0; o.y = p1;
        *(uint2*)((unsigned int*)h2s + (size_t)slice * NP * 8
                  + (size_t)rowB * 8 + fl * 2) = o;
    }
}

// ---------------------------------------------------------------------------
// gemm2: y2s[nt][row][16] = bf16(h2[row] @ W2[:,nt*16+..]). A-frags read
// from the sliced h2s layout: feat f -> slice f/16, idx f%16.
// ---------------------------------------------------------------------------
__global__ __launch_bounds__(256) void gemm2_kernel(
    const unsigned short* __restrict__ h2s,
    const unsigned short* __restrict__ W2t,
    unsigned short* __restrict__ y2s, int NP, int N)
{
    const int lane = threadIdx.x & 63;
    const int wave = threadIdx.x >> 6;
    const int quad = lane >> 4;
    const int l16  = lane & 15;
    const int row0 = blockIdx.x * 64 + wave * 16;
    int arow = row0 + l16;
    if (arow > N - 1) arow = N - 1;

    short8 af[4];
    #pragma unroll
    for (int kt = 0; kt < 4; ++kt) {
        int slice = kt * 2 + (quad >> 1);
        af[kt] = *(const short8*)(h2s + (size_t)slice * NP * 16
                                  + (size_t)arow * 16 + (quad & 1) * 8);
    }

    floatx4 acc[4];
    #pragma unroll
    for (int nt = 0; nt < 4; ++nt) acc[nt] = (floatx4){0.f, 0.f, 0.f, 0.f};

    #pragma unroll
    for (int nt = 0; nt < 4; ++nt) {
        const unsigned short* wp = W2t + (size_t)(nt * 16 + l16) * 128 + quad * 8;
        #pragma unroll
        for (int kt = 0; kt < 4; ++kt) {
            short8 bfr = *(const short8*)(wp + kt * 32);
            acc[nt] = __builtin_amdgcn_mfma_f32_16x16x32_bf16(
                af[kt], bfr, acc[nt], 0, 0, 0);
        }
    }

    #pragma unroll
    for (int nt = 0; nt < 4; ++nt) {
        #pragma unroll
        for (int r = 0; r < 4; ++r) {
            int row = row0 + quad * 4 + r;
            if (row < N)
                y2s[(size_t)nt * NP * 16 + (size_t)row * 16 + l16] =
                    f2bf(acc[nt][r]);
        }
    }
}

// ---------------------------------------------------------------------------
// spmm2_sliced v5: out[row][slice*16+..] = A @ y2s[slice] + b2[slice].
// 4 slices; same 2-group ILP structure; float4 NT output (64B full line).
// ---------------------------------------------------------------------------
__global__ __launch_bounds__(256) void spmm2_sliced(
    const int* __restrict__ deg, const int* __restrict__ dmax,
    const unsigned int* __restrict__ ell,
    const unsigned short* __restrict__ y2s, const float* __restrict__ b2,
    float* __restrict__ out, int NP, int N)
{
    const int slice = blockIdx.x & 3;
    const int blk   = blockIdx.x >> 2;
    const int wave  = threadIdx.x >> 6;
    const int lane  = threadIdx.x & 63;
    const int r     = lane >> 2;
    const int fl    = lane & 3;
    const int gA    = blk * 8 + wave;
    const int gB    = gA + 4;
    const int rowA  = gA * 16 + r;
    const int rowB  = gB * 16 + r;

    int dA = (rowA < N) ? deg[rowA] : 0;
    int dB = (rowB < N) ? deg[rowB] : 0;
    int nbA = (dmax[gA] + 3) >> 2;
    int nbB = (dmax[gB] + 3) >> 2;
    int nb = max(nbA, nbB);

    const uint4* egA = (const uint4*)ell + (size_t)gA * 256;
    const uint4* egB = (const uint4*)ell + (size_t)gB * 256;
    const unsigned int* xu = (const unsigned int*)y2s + (size_t)slice * NP * 8;

    float a0 = 0.f, a1 = 0.f, a2 = 0.f, a3 = 0.f;
    float c0 = 0.f, c1 = 0.f, c2 = 0.f, c3 = 0.f;

    for (int i4 = 0; i4 < nb; ++i4) {
        uint4 qa = make_uint4(0u, 0u, 0u, 0u);
        uint4 qb = make_uint4(0u, 0u, 0u, 0u);
        if (i4 < nbA) qa = egA[i4 * 16 + r];
        if (i4 < nbB) qb = egB[i4 * 16 + r];
        unsigned int sa[4] = {qa.x, qa.y, qa.z, qa.w};
        unsigned int sb[4] = {qb.x, qb.y, qb.z, qb.w};
        uint2 ua[4], ub[4];
        #pragma unroll
        for (int j = 0; j < 4; ++j) {
            sa[j] = (i4 * 4 + j < dA) ? sa[j] : 0u;
            ua[j] = *((const uint2*)(xu + (sa[j] & 0x1FFFFu) * 8) + fl);
        }
        #pragma unroll
        for (int j = 0; j < 4; ++j) {
            sb[j] = (i4 * 4 + j < dB) ? sb[j] : 0u;
            ub[j] = *((const uint2*)(xu + (sb[j] & 0x1FFFFu) * 8) + fl);
        }
        #pragma unroll
        for (int j = 0; j < 4; ++j) {
            float v = slotval(sa[j]);
            a0 = fmaf(v, bflo(ua[j].x), a0);
            a1 = fmaf(v, bfhi(ua[j].x), a1);
            a2 = fmaf(v, bflo(ua[j].y), a2);
            a3 = fmaf(v, bfhi(ua[j].y), a3);
        }
        #pragma unroll
        for (int j = 0; j < 4; ++j) {
            float v = slotval(sb[j]);
            c0 = fmaf(v, bflo(ub[j].x), c0);
            c1 = fmaf(v, bfhi(ub[j].x), c1);
            c2 = fmaf(v, bflo(ub[j].y), c2);
            c3 = fmaf(v, bfhi(ub[j].y), c3);
        }
    }

    float4 b = ((const float4*)b2)[slice * 4 + fl];
    if (rowA < N) {
        floatx4 o;
        o[0] = a0 + b.x; o[1] = a1 + b.y; o[2] = a2 + b.z; o[3] = a3 + b.w;
        __builtin_nontemporal_store(
            o, (floatx4*)(out + (size_t)rowA * 64 + slice * 16 + fl * 4));
    }
    if (rowB < N) {
        floatx4 o;
        o[0] = c0 + b.x; o[1] = c1 + b.y; o[2] = c2 + b.z; o[3] = c3 + b.w;
        __builtin_nontemporal_store(
            o, (floatx4*)(out + (size_t)rowB * 64 + slice * 16 + fl * 4));
    }
}

extern "C" void kernel_launch(void* const* d_in, const int* in_sizes, int n_in,
                              void* d_out, int out_size, void* d_ws, size_t ws_size,
                              hipStream_t stream)
{
    const float* x    = (const float*)d_in[0];
    const int*   erow = (const int*)  d_in[1];
    const int*   ecol = (const int*)  d_in[2];
    const float* eval = (const float*)d_in[3];
    const float* W1   = (const float*)d_in[4];
    const float* b1   = (const float*)d_in[5];
    const float* W2   = (const float*)d_in[6];
    const float* b2   = (const float*)d_in[7];
    float*       out  = (float*)d_out;

    const int N = in_sizes[0] / 128;   // 100000
    const int E = in_sizes[1];         // 1600000
    const int NP = N + 128;            // pad
    const int NB = (N + RW - 1) / RW;  // 391 buckets
    const int NC = (E + CH - 1) / CH;  // 391 chunks
    const int NGRP = NB * 16;          // 6256 16-row groups

    // Workspace (~91 MB). y2s aliases slab (slab dead after binB; 4KB
    // overflow lands in offsT, also dead after binB).
    unsigned short* y1s = (unsigned short*)d_ws;            // [8][NP][16]
    unsigned short* h2s = y1s + (size_t)NP * 128;           // [8][NP][16]
    unsigned short* W1t = h2s + (size_t)NP * 128;           // [128][128]
    unsigned short* W2t = W1t + 128 * 128;                  // [64][128]
    unsigned int* ell   = (unsigned int*)(W2t + 64 * 128);  // slot-major tiles
    uint2* slab         = (uint2*)(ell + (size_t)NB * RW * ELLS);  // [NC*CH]
    unsigned int* offsT = (unsigned int*)(slab + (size_t)NC * CH); // [NC*(NB+1)]
    int* deg            = (int*)(offsT + (size_t)NC * (NB + 1));   // [N]
    int* dmax           = deg + N;                          // [NGRP]
    unsigned short* y2s = (unsigned short*)slab;            // [4][NP][16] alias

    const int mfma_blocks = (N + 63) / 64;                // 1563
    const int prep_blocks = (128 * 128 + 255) / 256;      // 64
    const int gblk        = NGRP / 8;                     // 782 (NGRP%8==0)
    const int s1_blocks   = gblk * 8;                     // 6256
    const int s2_blocks   = gblk * 4;                     // 3128

    // ---- Prep: cast/transpose weights ----
    prep_kernel<<<prep_blocks, 256, 0, stream>>>(W1, W2, W1t, W2t);

    // ---- binA (chunk binning, coalesced slab) + gemm1 = bf16(x@W1) ----
    binA_gemm1_fused<<<NC + mfma_blocks, 256, 0, stream>>>(
        erow, ecol, eval, slab, offsT, E, NC, NB, x, W1t, y1s, NP, N);

    // ---- binB: bucket -> slot-major ELL tile in LDS -> coalesced flush ----
    binB<<<NB, 256, 0, stream>>>(slab, offsT, ell, deg, dmax, NC, NB, N);

    // ---- Layer-1 SpMM, XCD-sliced v5: h2s = relu(A@y1s + b1) ----
    spmm1_sliced<<<s1_blocks, 256, 0, stream>>>(
        deg, dmax, ell, y1s, b1, h2s, NP, N);

    // ---- gemm2: y2s = bf16(h2 @ W2) ----
    gemm2_kernel<<<mfma_blocks, 256, 0, stream>>>(h2s, W2t, y2s, NP, N);

    // ---- Layer-2 SpMM, XCD-sliced v5: out = A@y2s + b2 ----
    spmm2_sliced<<<s2_blocks, 256, 0, stream>>>(
        deg, dmax, ell, y2s, b2, out, NP, N);
}

// Round 16
// 294.112 us; speedup vs baseline: 1.2444x; 1.0788x over previous
//
#include <hip/hip_runtime.h>

// GCN forward, reassociated + bf16 tables + MFMA GEMMs + binned ELL build
// + XCD-feature-sliced SpMMs (v6: 32-feat slices, uint4 gathers, zero-pad):
//   y1s = bf16(x @ W1)            (MFMA, fused with binA; sliced [4][NP][32])
//   h2s = relu(A @ y1s + b1)      (sliced SpMM: 4 slices, 64B/row-slot gathers)
//   y2s = bf16(h2 @ W2)           (MFMA, sliced [2][NP][32])
//   out = A @ y2s + b2            (sliced SpMM, 2 slices, L2-resident)
// R24 resubmit (R15 was an infra failure). v5 proved the pin is L2 REQUEST
// RATE, not latency (ILP-doubling changed nothing; 8-slice 32B gathers =
// ~22M requests ~ 15/cy/XCD ~ port ceiling). v6: 4 slices x 32 feats ->
// lane gathers uint4 (16B), 4 lanes = 64B = ONE line per row-slot ->
// requests halved; slice redundancy halved. binB zero-inits its LDS tile ->
// pad slots are (col0,val0) -> per-slot predication + deg loads deleted.

typedef __attribute__((ext_vector_type(8))) short short8;
typedef __attribute__((ext_vector_type(4))) float floatx4;

#define ELLS 64    // ELL stride (slots/row)
#define RW   256   // rows per binB bucket (LDS tile 64 KB)
#define CH   4096  // edges per binA chunk
#define EPT  16    // edges per thread in binA (4096/256)
#define MAXB 400   // static LDS bound for bucket count (N=100K -> 391)

static __device__ __forceinline__ unsigned short f2bf(float f) {
    unsigned int u = __builtin_bit_cast(unsigned int, f);
    u += 0x7fffu + ((u >> 16) & 1u);        // round-to-nearest-even
    return (unsigned short)(u >> 16);
}
static __device__ __forceinline__ float bflo(unsigned int u) {
    return __builtin_bit_cast(float, u << 16);
}
static __device__ __forceinline__ float bfhi(unsigned int u) {
    return __builtin_bit_cast(float, u & 0xffff0000u);
}
// packed ELL slot: low 17 bits = col, high 15 bits = val*32767
static __device__ __forceinline__ float slotval(unsigned int s) {
    return (float)(s >> 17) * (1.0f / 32767.0f);
}

// ---------------------------------------------------------------------------
// Prep: W1[128,128] -> W1t[128][128] bf16; W2[128,64] -> W2t[64][128] bf16
// ---------------------------------------------------------------------------
__global__ __launch_bounds__(256) void prep_kernel(
    const float* __restrict__ W1, const float* __restrict__ W2,
    unsigned short* __restrict__ W1t, unsigned short* __restrict__ W2t)
{
    int idx = blockIdx.x * 256 + threadIdx.x;
    if (idx < 128 * 128) {
        int n = idx >> 7, k = idx & 127;
        W1t[idx] = f2bf(W1[(size_t)k * 128 + n]);
    }
    if (idx < 64 * 128) {
        int n = idx >> 7, k = idx & 127;
        W2t[idx] = f2bf(W2[(size_t)k * 64 + n]);
    }
}

// ---------------------------------------------------------------------------
// gemm1: y1s[slice4][row][32] = bf16(x[row] @ W1[:, slice*32 + ..]).
// Verified gfx950 layouts: A/B frag [lane&15][quad*8+j]; C/D col=lane&15,
// row=quad*4+reg. x read exactly once -> NT. nt covers feats nt*16..+16 ->
// slice = nt>>1, in-slice offset = (nt&1)*16.
// ---------------------------------------------------------------------------
static __device__ __forceinline__ void gemm1_body(
    const float* __restrict__ A, const unsigned short* __restrict__ Wt,
    unsigned short* __restrict__ Ys, int NP, int N, int bid)
{
    const int lane = threadIdx.x & 63;
    const int wave = threadIdx.x >> 6;
    const int quad = lane >> 4;
    const int l16  = lane & 15;
    const int row0 = bid * 64 + wave * 16;
    int arow = row0 + l16;
    if (arow > N - 1) arow = N - 1;      // clamp: stores guarded below

    short8 af[4];
    const float* ap = A + (size_t)arow * 128 + quad * 8;
    #pragma unroll
    for (int kt = 0; kt < 4; ++kt) {
        const floatx4* p = (const floatx4*)(ap + kt * 32);
        floatx4 lo = __builtin_nontemporal_load(p);
        floatx4 hi = __builtin_nontemporal_load(p + 1);
        short8 t;
        t[0] = (short)f2bf(lo[0]); t[1] = (short)f2bf(lo[1]);
        t[2] = (short)f2bf(lo[2]); t[3] = (short)f2bf(lo[3]);
        t[4] = (short)f2bf(hi[0]); t[5] = (short)f2bf(hi[1]);
        t[6] = (short)f2bf(hi[2]); t[7] = (short)f2bf(hi[3]);
        af[kt] = t;
    }

    floatx4 acc[8];
    #pragma unroll
    for (int nt = 0; nt < 8; ++nt) acc[nt] = (floatx4){0.f, 0.f, 0.f, 0.f};

    #pragma unroll
    for (int nt = 0; nt < 8; ++nt) {
        const unsigned short* wp = Wt + (size_t)(nt * 16 + l16) * 128 + quad * 8;
        #pragma unroll
        for (int kt = 0; kt < 4; ++kt) {
            short8 bfr = *(const short8*)(wp + kt * 32);
            acc[nt] = __builtin_amdgcn_mfma_f32_16x16x32_bf16(
                af[kt], bfr, acc[nt], 0, 0, 0);
        }
    }

    #pragma unroll
    for (int nt = 0; nt < 8; ++nt) {
        #pragma unroll
        for (int r = 0; r < 4; ++r) {
            int row = row0 + quad * 4 + r;
            if (row < N)
                Ys[(size_t)(nt >> 1) * NP * 32 + (size_t)row * 32
                   + (nt & 1) * 16 + l16] = f2bf(acc[nt][r]);
        }
    }
}

// ---------------------------------------------------------------------------
// Fused dispatch: blocks [0,NC): binA (histogram/compact/coalesced slab
// flush); blocks [NC,..): gemm1. slab entry: .x = col|(row_in_bucket<<17),
// .y = fp32 val bits.
// ---------------------------------------------------------------------------
__global__ __launch_bounds__(256) void binA_gemm1_fused(
    const int* __restrict__ erow, const int* __restrict__ ecol,
    const float* __restrict__ eval,
    uint2* __restrict__ slab, unsigned int* __restrict__ offsT,
    int E, int NC, int NB,
    const float* __restrict__ x, const unsigned short* __restrict__ W1t,
    unsigned short* __restrict__ y1s, int NP, int N)
{
    __shared__ unsigned int hist[MAXB + 1];
    __shared__ uint2 compact[CH];

    if ((int)blockIdx.x < NC) {
        const int t     = threadIdx.x;
        const int chunk = blockIdx.x;

        for (int i = t; i <= NB; i += 256) hist[i] = 0;
        __syncthreads();

        int base = chunk * CH + t * EPT;
        unsigned int w0[EPT];   // col | (row_in_bucket << 17)
        unsigned int vb[EPT];   // fp32 val bits
        int bk[EPT], rk[EPT];

        if (base + EPT <= E) {
            #pragma unroll
            for (int q = 0; q < 4; ++q) {
                int4   r4 = *(const int4*)(erow + base + q * 4);
                int4   c4 = *(const int4*)(ecol + base + q * 4);
                float4 v4 = *(const float4*)(eval + base + q * 4);
                int rr[4]   = {r4.x, r4.y, r4.z, r4.w};
                int cc[4]   = {c4.x, c4.y, c4.z, c4.w};
                float vv[4] = {v4.x, v4.y, v4.z, v4.w};
                #pragma unroll
                for (int j = 0; j < 4; ++j) {
                    int i = q * 4 + j;
                    bk[i] = rr[j] >> 8;
                    w0[i] = (unsigned int)cc[j]
                          | (((unsigned int)rr[j] & (RW - 1)) << 17);
                    vb[i] = __builtin_bit_cast(unsigned int, vv[j]);
                }
            }
        } else {
            #pragma unroll
            for (int j = 0; j < EPT; ++j) {
                int e = base + j;
                if (e < E) {
                    int r = erow[e];
                    bk[j] = r >> 8;
                    w0[j] = (unsigned int)ecol[e]
                          | (((unsigned int)r & (RW - 1)) << 17);
                    vb[j] = __builtin_bit_cast(unsigned int, eval[e]);
                } else {
                    bk[j] = NB;  // sentinel bucket, skipped by binB
                    w0[j] = 0u; vb[j] = 0u;
                }
            }
        }

        #pragma unroll
        for (int j = 0; j < EPT; ++j)
            rk[j] = (int)atomicAdd(&hist[bk[j]], 1u);
        __syncthreads();

        if (t == 0) {            // exclusive prefix over NB+1 buckets
            unsigned int run = 0;
            for (int i = 0; i <= NB; ++i) {
                unsigned int c = hist[i];
                hist[i] = run;
                run += c;
            }
        }
        __syncthreads();

        #pragma unroll
        for (int j = 0; j < EPT; ++j) {
            unsigned int pos = hist[bk[j]] + (unsigned int)rk[j];
            uint2 e; e.x = w0[j]; e.y = vb[j];
            compact[pos] = e;
        }
        __syncthreads();

        uint2* sp = slab + (size_t)chunk * CH;
        #pragma unroll
        for (int s = 0; s < EPT; ++s)
            sp[s * 256 + t] = compact[s * 256 + t];
        unsigned int* op = offsT + (size_t)chunk * (NB + 1);
        for (int i = t; i <= NB; i += 256) op[i] = hist[i];
    } else {
        gemm1_body(x, W1t, y1s, NP, N, blockIdx.x - NC);
    }
}

// ---------------------------------------------------------------------------
// binB: block b builds the ELL tile for rows [b*RW,(b+1)*RW) in LDS from the
// slab's per-chunk segments, then flushes SLOT-MAJOR:
//   dst per bucket: [grp 16][s4 16][r 16] x uint4  (grp = row group of 16)
// LDS tile is ZERO-INITIALIZED -> unfilled slots read back as (col0,val0),
// which lets the SpMMs drop all per-slot predication and deg loads.
// LDS store uses a 4-slot rotation swizzle (blk = (p/4 + rin) & 15); flush
// reads with the inverse, writes dst-contiguous. Emits dmax[group].
// ---------------------------------------------------------------------------
__global__ __launch_bounds__(256) void binB(
    const uint2* __restrict__ slab, const unsigned int* __restrict__ offsT,
    unsigned int* __restrict__ ell, int* __restrict__ dmax,
    int NC, int NB, int N)
{
    __shared__ unsigned int ell_lds[RW * ELLS];   // 64 KB
    __shared__ unsigned int cur[RW];

    const int t = threadIdx.x;
    const int b = blockIdx.x;

    uint4* z = (uint4*)ell_lds;
    #pragma unroll
    for (int i = 0; i < (RW * ELLS / 4) / 256; ++i)   // 16 steps
        z[i * 256 + t] = make_uint4(0u, 0u, 0u, 0u);
    for (int i = t; i < RW; i += 256) cur[i] = 0;
    __syncthreads();

    const int grp = t >> 5;     // 8 chunk-groups of 32 lanes
    const int sl  = t & 31;
    for (int cbase = 0; cbase < NC; cbase += 8) {
        int c = cbase + grp;
        if (c < NC) {
            const unsigned int* op = offsT + (size_t)c * (NB + 1) + b;
            unsigned int off = op[0];
            unsigned int end = op[1];
            const uint2* sp = slab + (size_t)c * CH;
            for (unsigned int i = off + (unsigned)sl; i < end; i += 32) {
                uint2 e = sp[i];
                unsigned int rin = e.x >> 17;
                unsigned int col = e.x & 0x1FFFFu;
                float v = __builtin_bit_cast(float, e.y);
                unsigned int q = (unsigned int)(int)(v * 32767.f + 0.5f);
                unsigned int p = atomicAdd(&cur[rin], 1u);
                if (p < ELLS) {
                    unsigned int blk = ((p >> 2) + rin) & 15u;  // swizzle
                    ell_lds[rin * ELLS + blk * 4 + (p & 3)] = col | (q << 17);
                }
            }
        }
    }
    __syncthreads();

    // slot-major flush: du = s*256 + s4*16 + r (uint4), dst-contiguous in t
    uint4* dst = (uint4*)(ell + (size_t)b * RW * ELLS);
    const int s4 = t >> 4;
    const int r  = t & 15;
    #pragma unroll
    for (int s = 0; s < 16; ++s) {
        unsigned int sblk = (unsigned)((s4 + r) & 15);
        uint4 q = *(const uint4*)(ell_lds + ((s * 16 + r) * ELLS + sblk * 4));
        dst[s * 256 + s4 * 16 + r] = q;
    }

    if (t < 16) {
        int m = 0;
        #pragma unroll
        for (int i = 0; i < 16; ++i)
            m = max(m, (int)cur[t * 16 + i]);
        dmax[b * 16 + t] = min(m, ELLS);
    }
}

// ---------------------------------------------------------------------------
// spmm1_sliced v6: h2s[slice4][row][32] = relu(A @ y1s[slice] + b1[slice]).
// grid = (NGRP/4) * 4 slices; slice = blockIdx&3 -> XCD pair affinity.
// Wave = 16-row group; lane = r(4b) x fl(2b); lane owns 8 feats. Per slot:
// ONE uint4 gather (4 lanes/row = 64B = one L2 line). No predication: pad
// slots are (col0,val0) by construction.
// ---------------------------------------------------------------------------
__global__ __launch_bounds__(256) void spmm1_sliced(
    const int* __restrict__ dmax, const unsigned int* __restrict__ ell,
    const unsigned short* __restrict__ y1s, const float* __restrict__ b1,
    unsigned short* __restrict__ h2s, int NP, int N)
{
    const int slice = blockIdx.x & 3;
    const int rblk  = blockIdx.x >> 2;
    const int wave  = threadIdx.x >> 6;
    const int lane  = threadIdx.x & 63;
    const int r     = lane >> 2;          // row within group (0..15)
    const int fl    = lane & 3;           // feat-octet (0..3): feats fl*8..+8
    const int g     = rblk * 4 + wave;    // 16-row group
    const int row   = g * 16 + r;

    int nb = (dmax[g] + 3) >> 2;

    const uint4* eg = (const uint4*)ell + (size_t)g * 256;
    const unsigned int* xu = (const unsigned int*)y1s + (size_t)slice * NP * 16;

    float a0 = 0.f, a1 = 0.f, a2 = 0.f, a3 = 0.f;
    float a4 = 0.f, a5 = 0.f, a6 = 0.f, a7 = 0.f;

    for (int i4 = 0; i4 < nb; ++i4) {
        uint4 q = eg[i4 * 16 + r];
        unsigned int s[4] = {q.x, q.y, q.z, q.w};
        uint4 u[4];
        #pragma unroll
        for (int j = 0; j < 4; ++j)
            u[j] = *((const uint4*)(xu + (s[j] & 0x1FFFFu) * 16) + fl);
        #pragma unroll
        for (int j = 0; j < 4; ++j) {
            float v = slotval(s[j]);
            a0 = fmaf(v, bflo(u[j].x), a0); a1 = fmaf(v, bfhi(u[j].x), a1);
            a2 = fmaf(v, bflo(u[j].y), a2); a3 = fmaf(v, bfhi(u[j].y), a3);
            a4 = fmaf(v, bflo(u[j].z), a4); a5 = fmaf(v, bfhi(u[j].z), a5);
            a6 = fmaf(v, bflo(u[j].w), a6); a7 = fmaf(v, bfhi(u[j].w), a7);
        }
    }

    if (row < N) {
        const float4* bp = (const float4*)b1 + slice * 8 + fl * 2;
        float4 bx = bp[0], by = bp[1];
        uint4 o;
        o.x = (unsigned int)f2bf(fmaxf(a0 + bx.x, 0.f))
            | ((unsigned int)f2bf(fmaxf(a1 + bx.y, 0.f)) << 16);
        o.y = (unsigned int)f2bf(fmaxf(a2 + bx.z, 0.f))
            | ((unsigned int)f2bf(fmaxf(a3 + bx.w, 0.f)) << 16);
        o.z = (unsigned int)f2bf(fmaxf(a4 + by.x, 0.f))
            | ((unsigned int)f2bf(fmaxf(a5 + by.y, 0.f)) << 16);
        o.w = (unsigned int)f2bf(fmaxf(a6 + by.z, 0.f))
            | ((unsigned int)f2bf(fmaxf(a7 + by.w, 0.f)) << 16);
        *(uint4*)((unsigned int*)h2s + (size_t)slice * NP * 16
                  + (size_t)row * 16 + fl * 4) = o;
    }
}

// ---------------------------------------------------------------------------
// gemm2: y2s[slice2][row][32] = bf16(h2[row] @ W2[:, ..]). A-frag kt covers
// feats kt*32 + quad*8 .. +8 -> slice = kt directly in the [4][NP][32] h2s.
// ---------------------------------------------------------------------------
__global__ __launch_bounds__(256) void gemm2_kernel(
    const unsigned short* __restrict__ h2s,
    const unsigned short* __restrict__ W2t,
    unsigned short* __restrict__ y2s, int NP, int N)
{
    const int lane = threadIdx.x & 63;
    const int wave = threadIdx.x >> 6;
    const int quad = lane >> 4;
    const int l16  = lane & 15;
    const int row0 = blockIdx.x * 64 + wave * 16;
    int arow = row0 + l16;
    if (arow > N - 1) arow = N - 1;

    short8 af[4];
    #pragma unroll
    for (int kt = 0; kt < 4; ++kt)
        af[kt] = *(const short8*)(h2s + (size_t)kt * NP * 32
                                  + (size_t)arow * 32 + quad * 8);

    floatx4 acc[4];
    #pragma unroll
    for (int nt = 0; nt < 4; ++nt) acc[nt] = (floatx4){0.f, 0.f, 0.f, 0.f};

    #pragma unroll
    for (int nt = 0; nt < 4; ++nt) {
        const unsigned short* wp = W2t + (size_t)(nt * 16 + l16) * 128 + quad * 8;
        #pragma unroll
        for (int kt = 0; kt < 4; ++kt) {
            short8 bfr = *(const short8*)(wp + kt * 32);
            acc[nt] = __builtin_amdgcn_mfma_f32_16x16x32_bf16(
                af[kt], bfr, acc[nt], 0, 0, 0);
        }
    }

    #pragma unroll
    for (int nt = 0; nt < 4; ++nt) {
        #pragma unroll
        for (int r = 0; r < 4; ++r) {
            int row = row0 + quad * 4 + r;
            if (row < N)
                y2s[(size_t)(nt >> 1) * NP * 32 + (size_t)row * 32
                    + (nt & 1) * 16 + l16] = f2bf(acc[nt][r]);
        }
    }
}

// ---------------------------------------------------------------------------
// spmm2_sliced v6: out[row][slice*32 + ..] = A @ y2s[slice] + b2[slice].
// 2 slices x 32 feats (3.2MB, fully L2-resident); same uint4-gather
// structure; output = two NT float4 stores (32B contiguous per lane).
// ---------------------------------------------------------------------------
__global__ __launch_bounds__(256) void spmm2_sliced(
    const int* __restrict__ dmax, const unsigned int* __restrict__ ell,
    const unsigned short* __restrict__ y2s, const float* __restrict__ b2,
    float* __restrict__ out, int NP, int N)
{
    const int slice = blockIdx.x & 1;
    const int rblk  = blockIdx.x >> 1;
    const int wave  = threadIdx.x >> 6;
    const int lane  = threadIdx.x & 63;
    const int r     = lane >> 2;
    const int fl    = lane & 3;
    const int g     = rblk * 4 + wave;
    const int row   = g * 16 + r;

    int nb = (dmax[g] + 3) >> 2;

    const uint4* eg = (const uint4*)ell + (size_t)g * 256;
    const unsigned int* xu = (const unsigned int*)y2s + (size_t)slice * NP * 16;

    float a0 = 0.f, a1 = 0.f, a2 = 0.f, a3 = 0.f;
    float a4 = 0.f, a5 = 0.f, a6 = 0.f, a7 = 0.f;

    for (int i4 = 0; i4 < nb; ++i4) {
        uint4 q = eg[i4 * 16 + r];
        unsigned int s[4] = {q.x, q.y, q.z, q.w};
        uint4 u[4];
        #pragma unroll
        for (int j = 0; j < 4; ++j)
            u[j] = *((const uint4*)(xu + (s[j] & 0x1FFFFu) * 16) + fl);
        #pragma unroll
        for (int j = 0; j < 4; ++j) {
            float v = slotval(s[j]);
            a0 = fmaf(v, bflo(u[j].x), a0); a1 = fmaf(v, bfhi(u[j].x), a1);
            a2 = fmaf(v, bflo(u[j].y), a2); a3 = fmaf(v, bfhi(u[j].y), a3);
            a4 = fmaf(v, bflo(u[j].z), a4); a5 = fmaf(v, bfhi(u[j].z), a5);
            a6 = fmaf(v, bflo(u[j].w), a6); a7 = fmaf(v, bfhi(u[j].w), a7);
        }
    }

    if (row < N) {
        const float4* bp = (const float4*)b2 + slice * 8 + fl * 2;
        float4 bx = bp[0], by = bp[1];
        float* op = out + (size_t)row * 64 + slice * 32 + fl * 8;
        floatx4 o0, o1;
        o0[0] = a0 + bx.x; o0[1] = a1 + bx.y;
        o0[2] = a2 + bx.z; o0[3] = a3 + bx.w;
        o1[0] = a4 + by.x; o1[1] = a5 + by.y;
        o1[2] = a6 + by.z; o1[3] = a7 + by.w;
        __builtin_nontemporal_store(o0, (floatx4*)op);
        __builtin_nontemporal_store(o1, (floatx4*)(op + 4));
    }
}

extern "C" void kernel_launch(void* const* d_in, const int* in_sizes, int n_in,
                              void* d_out, int out_size, void* d_ws, size_t ws_size,
                              hipStream_t stream)
{
    const float* x    = (const float*)d_in[0];
    const int*   erow = (const int*)  d_in[1];
    const int*   ecol = (const int*)  d_in[2];
    const float* eval = (const float*)d_in[3];
    const float* W1   = (const float*)d_in[4];
    const float* b1   = (const float*)d_in[5];
    const float* W2   = (const float*)d_in[6];
    const float* b2   = (const float*)d_in[7];
    float*       out  = (float*)d_out;

    const int N = in_sizes[0] / 128;   // 100000
    const int E = in_sizes[1];         // 1600000
    const int NP = N + 128;            // pad
    const int NB = (N + RW - 1) / RW;  // 391 buckets
    const int NC = (E + CH - 1) / CH;  // 391 chunks
    const int NGRP = NB * 16;          // 6256 16-row groups

    // Workspace (~91 MB). y2s aliases slab (slab dead after binB; overflow
    // lands in offsT, also dead after binB).
    unsigned short* y1s = (unsigned short*)d_ws;            // [4][NP][32]
    unsigned short* h2s = y1s + (size_t)NP * 128;           // [4][NP][32]
    unsigned short* W1t = h2s + (size_t)NP * 128;           // [128][128]
    unsigned short* W2t = W1t + 128 * 128;                  // [64][128]
    unsigned int* ell   = (unsigned int*)(W2t + 64 * 128);  // slot-major tiles
    uint2* slab         = (uint2*)(ell + (size_t)NB * RW * ELLS);  // [NC*CH]
    unsigned int* offsT = (unsigned int*)(slab + (size_t)NC * CH); // [NC*(NB+1)]
    int* dmax           = (int*)(offsT + (size_t)NC * (NB + 1));   // [NGRP]
    unsigned short* y2s = (unsigned short*)slab;            // [2][NP][32] alias

    const int mfma_blocks = (N + 63) / 64;                // 1563
    const int prep_blocks = (128 * 128 + 255) / 256;      // 64
    const int gblk        = NGRP / 4;                     // 1564
    const int s1_blocks   = gblk * 4;                     // 6256
    const int s2_blocks   = gblk * 2;                     // 3128

    // ---- Prep: cast/transpose weights ----
    prep_kernel<<<prep_blocks, 256, 0, stream>>>(W1, W2, W1t, W2t);

    // ---- binA (chunk binning, coalesced slab) + gemm1 = bf16(x@W1) ----
    binA_gemm1_fused<<<NC + mfma_blocks, 256, 0, stream>>>(
        erow, ecol, eval, slab, offsT, E, NC, NB, x, W1t, y1s, NP, N);

    // ---- binB: bucket -> zeroed slot-major ELL tile -> coalesced flush ----
    binB<<<NB, 256, 0, stream>>>(slab, offsT, ell, dmax, NC, NB, N);

    // ---- Layer-1 SpMM, 4x32-feat slices: h2s = relu(A@y1s + b1) ----
    spmm1_sliced<<<s1_blocks, 256, 0, stream>>>(
        dmax, ell, y1s, b1, h2s, NP, N);

    // ---- gemm2: y2s = bf16(h2 @ W2) ----
    gemm2_kernel<<<mfma_blocks, 256, 0, stream>>>(h2s, W2t, y2s, NP, N);

    // ---- Layer-2 SpMM, 2x32-feat slices: out = A@y2s + b2 ----
    spmm2_sliced<<<s2_blocks, 256, 0, stream>>>(
        dmax, ell, y2s, b2, out, NP, N);
}